// Round 1
// baseline (944.984 us; speedup 1.0000x reference)
//
#include <hip/hip_runtime.h>
#include <hip/hip_bf16.h>

// MoE: D=1024, H=1024, E=8, K=2; input (2,512,1024) fp32 -> T=1024 tokens, N=2048 dispatch rows.
#define DM 1024
#define HD 1024
#define NE 8
#define TK 2
#define NT 1024   // tokens
#define NR 2048   // dispatch rows = NT*TK

__device__ __forceinline__ float gelu_tanh(float x) {
    // JAX default gelu (approximate=True)
    float x3 = x * x * x;
    return 0.5f * x * (1.0f + tanhf(0.7978845608028654f * (x + 0.044715f * x3)));
}

// One wave (64 threads) per token: logits -> softmax -> top2
__global__ void moe_router(const float* __restrict__ x, const float* __restrict__ rw,
                           int* __restrict__ e_sel, float* __restrict__ p_sel) {
    int t = blockIdx.x;
    int lane = threadIdx.x;  // 0..63
    const float* xr = x + (size_t)t * DM;
    float acc[NE];
#pragma unroll
    for (int e = 0; e < NE; ++e) acc[e] = 0.0f;
    for (int d = lane; d < DM; d += 64) {
        float xv = xr[d];
        const float* r = rw + (size_t)d * NE;
#pragma unroll
        for (int e = 0; e < NE; ++e) acc[e] += xv * r[e];
    }
#pragma unroll
    for (int e = 0; e < NE; ++e) {
#pragma unroll
        for (int off = 32; off > 0; off >>= 1) acc[e] += __shfl_xor(acc[e], off);
    }
    if (lane == 0) {
        float m = acc[0];
#pragma unroll
        for (int e = 1; e < NE; ++e) m = fmaxf(m, acc[e]);
        float p[NE];
        float s = 0.0f;
#pragma unroll
        for (int e = 0; e < NE; ++e) { p[e] = __expf(acc[e] - m); s += p[e]; }
        float inv = 1.0f / s;
        // top-2, ties -> lower index (strict >)
        int i0 = 0;
#pragma unroll
        for (int e = 1; e < NE; ++e) if (p[e] > p[i0]) i0 = e;
        int i1 = (i0 == 0) ? 1 : 0;
#pragma unroll
        for (int e = 0; e < NE; ++e) if (e != i1 && e != i0 && p[e] > p[i1]) i1 = e;
        e_sel[2 * t + 0] = i0;
        e_sel[2 * t + 1] = i1;
        p_sel[2 * t + 0] = p[i0] * inv;
        p_sel[2 * t + 1] = p[i1] * inv;
    }
}

// Layer 1: one block per dispatch row n. h[n][:] = gelu(x[tok(n)] @ w_in[e] + b_in[e])
__global__ __launch_bounds__(256) void moe_layer1(const float* __restrict__ x,
                                                  const float* __restrict__ w_in,
                                                  const float* __restrict__ b_in,
                                                  const int* __restrict__ e_sel,
                                                  float* __restrict__ h) {
    __shared__ float xs[DM];
    int n = blockIdx.x;
    int t = n >> 1;
    int e = e_sel[n];
    const float* xr = x + (size_t)t * DM;
    for (int d = threadIdx.x; d < DM; d += 256) xs[d] = xr[d];
    __syncthreads();
    const float* w = w_in + (size_t)e * DM * HD;
    int j = threadIdx.x;
    float a0 = 0.f, a1 = 0.f, a2 = 0.f, a3 = 0.f;
    for (int d = 0; d < DM; ++d) {
        float xv = xs[d];
        const float* wr = w + (size_t)d * HD;
        a0 = fmaf(xv, wr[j], a0);
        a1 = fmaf(xv, wr[j + 256], a1);
        a2 = fmaf(xv, wr[j + 512], a2);
        a3 = fmaf(xv, wr[j + 768], a3);
    }
    const float* b = b_in + (size_t)e * HD;
    float* hr = h + (size_t)n * HD;
    hr[j]       = gelu_tanh(a0 + b[j]);
    hr[j + 256] = gelu_tanh(a1 + b[j + 256]);
    hr[j + 512] = gelu_tanh(a2 + b[j + 512]);
    hr[j + 768] = gelu_tanh(a3 + b[j + 768]);
}

// Layer 2 + combine: one block per token; computes both expert rows, writes out directly.
__global__ __launch_bounds__(256) void moe_layer2(const float* __restrict__ h,
                                                  const float* __restrict__ w_out,
                                                  const float* __restrict__ b_out,
                                                  const int* __restrict__ e_sel,
                                                  const float* __restrict__ p_sel,
                                                  float* __restrict__ out) {
    __shared__ float hs0[HD];
    __shared__ float hs1[HD];
    int t = blockIdx.x;
    const float* h0 = h + (size_t)(2 * t) * HD;
    const float* h1 = h + (size_t)(2 * t + 1) * HD;
    for (int d = threadIdx.x; d < HD; d += 256) { hs0[d] = h0[d]; hs1[d] = h1[d]; }
    __syncthreads();
    int e0 = e_sel[2 * t], e1 = e_sel[2 * t + 1];
    float p0 = p_sel[2 * t], p1 = p_sel[2 * t + 1];
    const float* w0 = w_out + (size_t)e0 * HD * DM;
    const float* w1 = w_out + (size_t)e1 * HD * DM;
    int j = threadIdx.x;
    float a0 = 0.f, a1 = 0.f, a2 = 0.f, a3 = 0.f;
    float c0 = 0.f, c1 = 0.f, c2 = 0.f, c3 = 0.f;
    for (int d = 0; d < HD; ++d) {
        float h0v = hs0[d];
        float h1v = hs1[d];
        const float* w0r = w0 + (size_t)d * DM;
        const float* w1r = w1 + (size_t)d * DM;
        a0 = fmaf(h0v, w0r[j], a0);
        a1 = fmaf(h0v, w0r[j + 256], a1);
        a2 = fmaf(h0v, w0r[j + 512], a2);
        a3 = fmaf(h0v, w0r[j + 768], a3);
        c0 = fmaf(h1v, w1r[j], c0);
        c1 = fmaf(h1v, w1r[j + 256], c1);
        c2 = fmaf(h1v, w1r[j + 512], c2);
        c3 = fmaf(h1v, w1r[j + 768], c3);
    }
    const float* b0 = b_out + (size_t)e0 * DM;
    const float* b1 = b_out + (size_t)e1 * DM;
    float* o = out + (size_t)t * DM;
    o[j]       = p0 * (a0 + b0[j])       + p1 * (c0 + b1[j]);
    o[j + 256] = p0 * (a1 + b0[j + 256]) + p1 * (c1 + b1[j + 256]);
    o[j + 512] = p0 * (a2 + b0[j + 512]) + p1 * (c2 + b1[j + 512]);
    o[j + 768] = p0 * (a3 + b0[j + 768]) + p1 * (c3 + b1[j + 768]);
}

extern "C" void kernel_launch(void* const* d_in, const int* in_sizes, int n_in,
                              void* d_out, int out_size, void* d_ws, size_t ws_size,
                              hipStream_t stream) {
    const float* x     = (const float*)d_in[0];
    const float* rw    = (const float*)d_in[1];
    const float* w_in  = (const float*)d_in[2];
    const float* b_in  = (const float*)d_in[3];
    const float* w_out = (const float*)d_in[4];
    const float* b_out = (const float*)d_in[5];
    float* out = (float*)d_out;

    // ws layout: e_sel [NR] int | p_sel [NR] float | h [NR*HD] float
    char* ws = (char*)d_ws;
    int* e_sel   = (int*)ws;
    float* p_sel = (float*)(ws + NR * sizeof(int));
    float* h     = (float*)(ws + NR * sizeof(int) + NR * sizeof(float));

    moe_router<<<NT, 64, 0, stream>>>(x, rw, e_sel, p_sel);
    moe_layer1<<<NR, 256, 0, stream>>>(x, w_in, b_in, e_sel, h);
    moe_layer2<<<NT, 256, 0, stream>>>(h, w_out, b_out, e_sel, p_sel, out);
}

// Round 2
// 112.598 us; speedup vs baseline: 8.3925x; 8.3925x over previous
//
#include <hip/hip_runtime.h>
#include <hip/hip_bf16.h>

// MoE: D=1024, H=1024, E=8, K=2; T=1024 tokens, N=2048 dispatch rows.
#define DM 1024
#define HD 1024
#define NE 8
#define NT 1024
#define NR 2048
#define BM 64
#define BN 64
#define BKK 64
#define LDK 72          // padded LDS K-stride (bf16 elems): stride 144B -> 2-way bank alias (free)
#define MT_MAX 40       // max M-tiles: 2048/64 + 8 experts' padding
#define PN_MAX (MT_MAX * BM)  // 2560 padded rows

typedef __attribute__((ext_vector_type(8))) short short8;
typedef __attribute__((ext_vector_type(4))) float f32x4;

__device__ __forceinline__ float gelu_tanh(float x) {
    float x3 = x * x * x;
    return 0.5f * x * (1.0f + tanhf(0.7978845608028654f * (x + 0.044715f * x3)));
}

// ---------------- router: one wave per token ----------------
__global__ void moe_router(const float* __restrict__ x, const float* __restrict__ rw,
                           int* __restrict__ e_sel, float* __restrict__ p_sel) {
    int t = blockIdx.x;
    int lane = threadIdx.x;
    const float* xr = x + (size_t)t * DM;
    float acc[NE];
#pragma unroll
    for (int e = 0; e < NE; ++e) acc[e] = 0.0f;
    for (int d = lane; d < DM; d += 64) {
        float xv = xr[d];
        const float* r = rw + (size_t)d * NE;
#pragma unroll
        for (int e = 0; e < NE; ++e) acc[e] += xv * r[e];
    }
#pragma unroll
    for (int e = 0; e < NE; ++e) {
#pragma unroll
        for (int off = 32; off > 0; off >>= 1) acc[e] += __shfl_xor(acc[e], off);
    }
    if (lane == 0) {
        float m = acc[0];
#pragma unroll
        for (int e = 1; e < NE; ++e) m = fmaxf(m, acc[e]);
        float p[NE];
        float s = 0.0f;
#pragma unroll
        for (int e = 0; e < NE; ++e) { p[e] = __expf(acc[e] - m); s += p[e]; }
        float inv = 1.0f / s;
        int i0 = 0;
#pragma unroll
        for (int e = 1; e < NE; ++e) if (p[e] > p[i0]) i0 = e;
        int i1 = (i0 == 0) ? 1 : 0;
#pragma unroll
        for (int e = 0; e < NE; ++e) if (e != i1 && e != i0 && p[e] > p[i1]) i1 = e;
        e_sel[2 * t + 0] = i0;
        e_sel[2 * t + 1] = i1;
        p_sel[2 * t + 0] = p[i0] * inv;
        p_sel[2 * t + 1] = p[i1] * inv;
    }
}

// ---------------- setup: histogram, padded offsets, tile->expert map ----------------
// meta: [0..7]=ctr (zeroed), [8..15]=poff, [16..16+MT_MAX)=mt_expert
__global__ void moe_setup(const int* __restrict__ e_sel, int* __restrict__ meta,
                          int* __restrict__ sorted_tok) {
    __shared__ int scnt[NE];
    int tid = threadIdx.x;
    if (tid < NE) scnt[tid] = 0;
    __syncthreads();
    for (int i = tid; i < NR; i += 256) atomicAdd(&scnt[e_sel[i]], 1);
    __syncthreads();
    if (tid == 0) {
        int off = 0, tc = 0;
        for (int e = 0; e < NE; ++e) {
            meta[e] = 0;
            meta[8 + e] = off;
            int nt = (scnt[e] + BM - 1) / BM;
            for (int t = 0; t < nt; ++t) meta[16 + tc++] = e;
            off += nt * BM;
        }
        for (; tc < MT_MAX; ++tc) meta[16 + tc] = -1;
    }
    for (int i = tid; i < PN_MAX; i += 256) sorted_tok[i] = -1;
}

// ---------------- scatter rows to expert-sorted positions ----------------
__global__ void moe_scatter(const int* __restrict__ e_sel, int* __restrict__ meta,
                            int* __restrict__ sorted_tok, int* __restrict__ pos_of_row) {
    int n = blockIdx.x * 256 + threadIdx.x;
    if (n >= NR) return;
    int e = e_sel[n];
    int r = atomicAdd(&meta[e], 1);
    int pos = meta[8 + e] + r;
    sorted_tok[pos] = n >> 1;
    pos_of_row[n] = pos;
}

// ---------------- gather x (fp32) -> xg (bf16) at sorted positions ----------------
__global__ __launch_bounds__(256) void moe_gather(const float* __restrict__ x,
                                                  const int* __restrict__ sorted_tok,
                                                  __hip_bfloat16* __restrict__ xg) {
    int pos = blockIdx.x;
    int t = sorted_tok[pos];
    int j = threadIdx.x * 4;
    ushort4 u;
    if (t >= 0) {
        float4 f = *(const float4*)(x + (size_t)t * DM + j);
        __hip_bfloat16 b0 = __float2bfloat16(f.x), b1 = __float2bfloat16(f.y);
        __hip_bfloat16 b2 = __float2bfloat16(f.z), b3 = __float2bfloat16(f.w);
        u.x = *(unsigned short*)&b0; u.y = *(unsigned short*)&b1;
        u.z = *(unsigned short*)&b2; u.w = *(unsigned short*)&b3;
    } else {
        u.x = u.y = u.z = u.w = 0;
    }
    *(ushort4*)((unsigned short*)xg + (size_t)pos * DM + j) = u;
}

// ---------------- grouped GEMM: 64x64 tile, 4 waves, mfma 16x16x32 bf16 ----------------
// A [PN_MAX][1024] bf16 row-major. W [NE][K=1024][N=1024] fp32 row-major (converted+
// transposed to bf16 in-register during LDS staging). EPI=0: H=gelu(AW+b) bf16.
// EPI=1: Y=AW+b fp32.
template <int EPI>
__global__ __launch_bounds__(256) void moe_gemm(const __hip_bfloat16* __restrict__ A,
                                                const float* __restrict__ W,
                                                const float* __restrict__ bias,
                                                const int* __restrict__ meta,
                                                __hip_bfloat16* __restrict__ Hout,
                                                float* __restrict__ Yout) {
    int mt = blockIdx.y;
    int e = meta[16 + mt];
    if (e < 0) return;
    int nb = blockIdx.x;

    __shared__ __align__(16) __hip_bfloat16 As[2][BM][LDK];
    __shared__ __align__(16) __hip_bfloat16 Bs[2][BN][LDK];

    int tid = threadIdx.x;
    int wid = tid >> 6, lane = tid & 63;
    int wm = wid >> 1, wn = wid & 1;

    const __hip_bfloat16* Ab = A + (size_t)mt * BM * DM;
    const float* Wb = W + (size_t)e * DM * HD + (size_t)nb * BN;

    uint4 ra[2];
    float4 rb[4];

    auto GLOAD = [&](int kt) {
#pragma unroll
        for (int i = 0; i < 2; ++i) {
            int c = tid + 256 * i;
            int row = c >> 3, col8 = c & 7;
            ra[i] = *(const uint4*)((const unsigned short*)Ab + (size_t)row * DM + kt * BKK + col8 * 8);
        }
#pragma unroll
        for (int i = 0; i < 4; ++i) {
            int c = tid + 256 * i;
            int kr = c >> 4, c4 = c & 15;
            rb[i] = *(const float4*)(Wb + (size_t)(kt * BKK + kr) * HD + c4 * 4);
        }
    };
    auto STORE = [&](int b) {
#pragma unroll
        for (int i = 0; i < 2; ++i) {
            int c = tid + 256 * i;
            int row = c >> 3, col8 = c & 7;
            *(uint4*)&As[b][row][col8 * 8] = ra[i];
        }
#pragma unroll
        for (int i = 0; i < 4; ++i) {
            int c = tid + 256 * i;
            int kr = c >> 4, c4 = c & 15;
            Bs[b][c4 * 4 + 0][kr] = __float2bfloat16(rb[i].x);
            Bs[b][c4 * 4 + 1][kr] = __float2bfloat16(rb[i].y);
            Bs[b][c4 * 4 + 2][kr] = __float2bfloat16(rb[i].z);
            Bs[b][c4 * 4 + 3][kr] = __float2bfloat16(rb[i].w);
        }
    };

    f32x4 acc[2][2] = {};

    GLOAD(0);
    STORE(0);
    __syncthreads();
    int buf = 0;
    const int NK = DM / BKK;  // 16
    for (int kt = 0; kt < NK; ++kt) {
        if (kt + 1 < NK) GLOAD(kt + 1);
#pragma unroll
        for (int kk = 0; kk < 2; ++kk) {
            int kb = kk * 32 + (lane >> 4) * 8;
            short8 a0 = *(const short8*)&As[buf][wm * 32 + (lane & 15)][kb];
            short8 a1 = *(const short8*)&As[buf][wm * 32 + 16 + (lane & 15)][kb];
            short8 b0 = *(const short8*)&Bs[buf][wn * 32 + (lane & 15)][kb];
            short8 b1 = *(const short8*)&Bs[buf][wn * 32 + 16 + (lane & 15)][kb];
            acc[0][0] = __builtin_amdgcn_mfma_f32_16x16x32_bf16(a0, b0, acc[0][0], 0, 0, 0);
            acc[0][1] = __builtin_amdgcn_mfma_f32_16x16x32_bf16(a0, b1, acc[0][1], 0, 0, 0);
            acc[1][0] = __builtin_amdgcn_mfma_f32_16x16x32_bf16(a1, b0, acc[1][0], 0, 0, 0);
            acc[1][1] = __builtin_amdgcn_mfma_f32_16x16x32_bf16(a1, b1, acc[1][1], 0, 0, 0);
        }
        if (kt + 1 < NK) {
            STORE(buf ^ 1);
            __syncthreads();
            buf ^= 1;
        }
    }

    // epilogue: C/D layout col=lane&15, row=(lane>>4)*4+r
    int row0 = mt * BM + wm * 32 + ((lane >> 4) << 2);
    int col0 = nb * BN + wn * 32 + (lane & 15);
    const float* be = bias + (size_t)e * HD;
#pragma unroll
    for (int fm = 0; fm < 2; ++fm) {
#pragma unroll
        for (int fn = 0; fn < 2; ++fn) {
            int c = col0 + fn * 16;
            float bv = be[c];
#pragma unroll
            for (int r = 0; r < 4; ++r) {
                int rr = row0 + fm * 16 + r;
                float v = acc[fm][fn][r] + bv;
                if (EPI == 0) {
                    Hout[(size_t)rr * HD + c] = __float2bfloat16(gelu_tanh(v));
                } else {
                    Yout[(size_t)rr * HD + c] = v;
                }
            }
        }
    }
}

// ---------------- combine: out[t] = p0*y[pos0] + p1*y[pos1] ----------------
__global__ __launch_bounds__(256) void moe_combine(const float* __restrict__ y,
                                                   const float* __restrict__ p_sel,
                                                   const int* __restrict__ pos_of_row,
                                                   float* __restrict__ out) {
    int t = blockIdx.x;
    int j = threadIdx.x * 4;
    int q0 = pos_of_row[2 * t], q1 = pos_of_row[2 * t + 1];
    float p0 = p_sel[2 * t], p1 = p_sel[2 * t + 1];
    float4 a = *(const float4*)(y + (size_t)q0 * DM + j);
    float4 b = *(const float4*)(y + (size_t)q1 * DM + j);
    float4 o;
    o.x = p0 * a.x + p1 * b.x;
    o.y = p0 * a.y + p1 * b.y;
    o.z = p0 * a.z + p1 * b.z;
    o.w = p0 * a.w + p1 * b.w;
    *(float4*)(out + (size_t)t * DM + j) = o;
}

// ---------------- fallback (round-1) kernels, used if ws is too small ----------------
__global__ __launch_bounds__(256) void moe_layer1(const float* __restrict__ x,
                                                  const float* __restrict__ w_in,
                                                  const float* __restrict__ b_in,
                                                  const int* __restrict__ e_sel,
                                                  float* __restrict__ h) {
    __shared__ float xs[DM];
    int n = blockIdx.x;
    int t = n >> 1;
    int e = e_sel[n];
    const float* xr = x + (size_t)t * DM;
    for (int d = threadIdx.x; d < DM; d += 256) xs[d] = xr[d];
    __syncthreads();
    const float* w = w_in + (size_t)e * DM * HD;
    int j = threadIdx.x;
    float a0 = 0.f, a1 = 0.f, a2 = 0.f, a3 = 0.f;
    for (int d = 0; d < DM; ++d) {
        float xv = xs[d];
        const float* wr = w + (size_t)d * HD;
        a0 = fmaf(xv, wr[j], a0);
        a1 = fmaf(xv, wr[j + 256], a1);
        a2 = fmaf(xv, wr[j + 512], a2);
        a3 = fmaf(xv, wr[j + 768], a3);
    }
    const float* b = b_in + (size_t)e * HD;
    float* hr = h + (size_t)n * HD;
    hr[j]       = gelu_tanh(a0 + b[j]);
    hr[j + 256] = gelu_tanh(a1 + b[j + 256]);
    hr[j + 512] = gelu_tanh(a2 + b[j + 512]);
    hr[j + 768] = gelu_tanh(a3 + b[j + 768]);
}

__global__ __launch_bounds__(256) void moe_layer2(const float* __restrict__ h,
                                                  const float* __restrict__ w_out,
                                                  const float* __restrict__ b_out,
                                                  const int* __restrict__ e_sel,
                                                  const float* __restrict__ p_sel,
                                                  float* __restrict__ out) {
    __shared__ float hs0[HD];
    __shared__ float hs1[HD];
    int t = blockIdx.x;
    const float* h0 = h + (size_t)(2 * t) * HD;
    const float* h1 = h + (size_t)(2 * t + 1) * HD;
    for (int d = threadIdx.x; d < HD; d += 256) { hs0[d] = h0[d]; hs1[d] = h1[d]; }
    __syncthreads();
    int e0 = e_sel[2 * t], e1 = e_sel[2 * t + 1];
    float p0 = p_sel[2 * t], p1 = p_sel[2 * t + 1];
    const float* w0 = w_out + (size_t)e0 * HD * DM;
    const float* w1 = w_out + (size_t)e1 * HD * DM;
    int j = threadIdx.x;
    float a0 = 0.f, a1 = 0.f, a2 = 0.f, a3 = 0.f;
    float c0 = 0.f, c1 = 0.f, c2 = 0.f, c3 = 0.f;
    for (int d = 0; d < HD; ++d) {
        float h0v = hs0[d];
        float h1v = hs1[d];
        const float* w0r = w0 + (size_t)d * DM;
        const float* w1r = w1 + (size_t)d * DM;
        a0 = fmaf(h0v, w0r[j], a0);
        a1 = fmaf(h0v, w0r[j + 256], a1);
        a2 = fmaf(h0v, w0r[j + 512], a2);
        a3 = fmaf(h0v, w0r[j + 768], a3);
        c0 = fmaf(h1v, w1r[j], c0);
        c1 = fmaf(h1v, w1r[j + 256], c1);
        c2 = fmaf(h1v, w1r[j + 512], c2);
        c3 = fmaf(h1v, w1r[j + 768], c3);
    }
    const float* b0 = b_out + (size_t)e0 * DM;
    const float* b1 = b_out + (size_t)e1 * DM;
    float* o = out + (size_t)t * DM;
    o[j]       = p0 * (a0 + b0[j])       + p1 * (c0 + b1[j]);
    o[j + 256] = p0 * (a1 + b0[j + 256]) + p1 * (c1 + b1[j + 256]);
    o[j + 512] = p0 * (a2 + b0[j + 512]) + p1 * (c2 + b1[j + 512]);
    o[j + 768] = p0 * (a3 + b0[j + 768]) + p1 * (c3 + b1[j + 768]);
}

extern "C" void kernel_launch(void* const* d_in, const int* in_sizes, int n_in,
                              void* d_out, int out_size, void* d_ws, size_t ws_size,
                              hipStream_t stream) {
    const float* x     = (const float*)d_in[0];
    const float* rw    = (const float*)d_in[1];
    const float* w_in  = (const float*)d_in[2];
    const float* b_in  = (const float*)d_in[3];
    const float* w_out = (const float*)d_in[4];
    const float* b_out = (const float*)d_in[5];
    float* out = (float*)d_out;

    char* ws = (char*)d_ws;
    // layout: e_sel 8KB | p_sel 8KB | meta 1KB | sorted_tok 10KB | pos_of_row 8KB | pad->64KB
    //         h bf16 5.24MB | xg bf16 5.24MB (y fp32 10.49MB overlays xg + 5.24MB more)
    int*   e_sel      = (int*)ws;
    float* p_sel      = (float*)(ws + 8 * 1024);
    int*   meta       = (int*)(ws + 16 * 1024);
    int*   sorted_tok = (int*)(ws + 17 * 1024);
    int*   pos_of_row = (int*)(ws + 27 * 1024);
    __hip_bfloat16* h  = (__hip_bfloat16*)(ws + 64 * 1024);
    __hip_bfloat16* xg = (__hip_bfloat16*)(ws + 64 * 1024 + (size_t)PN_MAX * DM * 2);
    float* y           = (float*)(ws + 64 * 1024 + (size_t)PN_MAX * DM * 2);  // overlays xg (xg dead by then)

    const size_t NEED = 64 * 1024 + (size_t)PN_MAX * DM * 2 + (size_t)PN_MAX * DM * 4;

    if (ws_size >= NEED) {
        moe_router<<<NT, 64, 0, stream>>>(x, rw, e_sel, p_sel);
        moe_setup<<<1, 256, 0, stream>>>(e_sel, meta, sorted_tok);
        moe_scatter<<<NR / 256, 256, 0, stream>>>(e_sel, meta, sorted_tok, pos_of_row);
        moe_gather<<<PN_MAX, 256, 0, stream>>>(x, sorted_tok, xg);
        dim3 grid(HD / BN, MT_MAX);
        moe_gemm<0><<<grid, 256, 0, stream>>>(xg, w_in, b_in, meta, h, nullptr);
        moe_gemm<1><<<grid, 256, 0, stream>>>(h, w_out, b_out, meta, nullptr, y);
        moe_combine<<<NT, 256, 0, stream>>>(y, p_sel, pos_of_row, out);
    } else {
        // fallback: round-1 path (needs ~8.4MB)
        float* hf = (float*)(ws + 16 * 1024);
        moe_router<<<NT, 64, 0, stream>>>(x, rw, e_sel, p_sel);
        moe_layer1<<<NR, 256, 0, stream>>>(x, w_in, b_in, e_sel, hf);
        moe_layer2<<<NT, 256, 0, stream>>>(hf, w_out, b_out, e_sel, p_sel, out);
    }
}